// Round 10
// baseline (798.301 us; speedup 1.0000x reference)
//
#include <hip/hip_runtime.h>

#define HD 128

typedef __attribute__((ext_vector_type(8))) short bf16x8v;
typedef __attribute__((ext_vector_type(4))) float f32x4v;

__device__ __forceinline__ unsigned short f2bf(float f) {
  unsigned int u = __float_as_uint(f);
  u += 0x7FFFu + ((u >> 16) & 1u);   // RNE
  return (unsigned short)(u >> 16);
}
__device__ __forceinline__ float bf2f(unsigned short h) {
  return __uint_as_float(((unsigned int)h) << 16);
}
__device__ __forceinline__ float bflo(unsigned int u) { return __uint_as_float(u << 16); }
__device__ __forceinline__ float bfhi(unsigned int u) { return __uint_as_float(u & 0xFFFF0000u); }
__device__ __forceinline__ unsigned int packbf(float a, float b) {
  return (unsigned int)f2bf(a) | ((unsigned int)f2bf(b) << 16);
}

// ===================== graph preprocessing =====================

// sliced histogram: block owns a bin range, scans all keys, dense non-atomic write
#define HSLICE 16
__global__ __launch_bounds__(1024) void hist_slice(
    const int* __restrict__ row, const int* __restrict__ col,
    int* __restrict__ cnt_in, int* __restrict__ outdeg, int n, int e) {
  __shared__ int hbin[2560];
  int b = blockIdx.x;
  const int* keys = (b < HSLICE) ? col : row;
  int* outp = (b < HSLICE) ? cnt_in : outdeg;
  int sb = b & (HSLICE - 1);
  int per = (n + HSLICE - 1) / HSLICE;
  int lo = sb * per, hi = min(n, lo + per);
  int cnt = hi - lo;
  for (int i = threadIdx.x; i < cnt; i += 1024) hbin[i] = 0;
  __syncthreads();
  for (int i = threadIdx.x; i < e; i += 1024) {
    int k = keys[i];
    if (k >= lo && k < hi) atomicAdd(&hbin[k - lo], 1);
  }
  __syncthreads();
  for (int i = threadIdx.x; i < cnt; i += 1024) outp[lo + i] = hbin[i];
}

// fallback (unused when n fits slices)
__global__ void hist_kernel(const int* __restrict__ row, const int* __restrict__ col,
                            int* __restrict__ cnt_in, int* __restrict__ outdeg, int e) {
  int i = blockIdx.x * blockDim.x + threadIdx.x;
  if (i < e) { atomicAdd(&cnt_in[col[i]], 1); atomicAdd(&outdeg[row[i]], 1); }
}

__global__ void scan1(const int* __restrict__ cnt, int n, int* __restrict__ sums) {
  __shared__ int lds[256];
  int b = blockIdx.x, t = threadIdx.x;
  int base = b * 1024 + t * 4;
  int s = 0;
#pragma unroll
  for (int m = 0; m < 4; m++) if (base + m < n) s += cnt[base + m];
  lds[t] = s;
  __syncthreads();
  for (int d = 128; d > 0; d >>= 1) {
    if (t < d) lds[t] += lds[t + d];
    __syncthreads();
  }
  if (t == 0) sums[b] = lds[0];
}

__global__ void scan2(const int* __restrict__ sums, int nc, int* __restrict__ off) {
  int l = threadIdx.x;
  int v = (l < nc) ? sums[l] : 0;
  int x = v;
#pragma unroll
  for (int d = 1; d < 64; d <<= 1) {
    int y = __shfl_up(x, d, 64);
    if (l >= d) x += y;
  }
  if (l < nc) off[l] = x - v;  // exclusive
}

__global__ void scan3(const int* __restrict__ cnt, int n, const int* __restrict__ off,
                      int* __restrict__ ptr, int* __restrict__ cursor) {
  __shared__ int lds[256];
  int b = blockIdx.x, t = threadIdx.x;
  int base = b * 1024 + t * 4;
  int v[4], p[4];
#pragma unroll
  for (int m = 0; m < 4; m++) v[m] = (base + m < n) ? cnt[base + m] : 0;
  p[0] = v[0];
#pragma unroll
  for (int m = 1; m < 4; m++) p[m] = p[m - 1] + v[m];
  int tsum = p[3];
  lds[t] = tsum;
  __syncthreads();
  for (int d = 1; d < 256; d <<= 1) {
    int y = 0;
    if (t >= d) y = lds[t - d];
    __syncthreads();
    lds[t] += y;
    __syncthreads();
  }
  int basev = off[b] + lds[t] - tsum;
  if (b == 0 && t == 0) ptr[0] = 0;
#pragma unroll
  for (int m = 0; m < 4; m++) {
    int i = base + m;
    if (i < n) {
      int incl = basev + p[m];
      ptr[i + 1] = incl;
      cursor[i] = incl - v[m];
    }
  }
}

// R8 form: separate scatter arrays (measured faster than packed int2)
__global__ void place_both(const int* __restrict__ row, const int* __restrict__ col,
                           int* __restrict__ cursor, int* __restrict__ cursor2,
                           int* __restrict__ csr_src, int* __restrict__ csr_dst,
                           int* __restrict__ csr_eid, int* __restrict__ csr2_eid, int e) {
  int i = blockIdx.x * blockDim.x + threadIdx.x;
  if (i < e) {
    int r = row[i], c = col[i];
    int pos = atomicAdd(&cursor[c], 1);
    csr_src[pos] = r;
    csr_dst[pos] = c;
    csr_eid[pos] = i;
    int pos2 = atomicAdd(&cursor2[r], 1);
    csr2_eid[pos2] = i;
  }
}

__global__ void dinv1_kernel(const int* __restrict__ outdeg, float* __restrict__ dinv1, int n) {
  int i = blockIdx.x * blockDim.x + threadIdx.x;
  if (i < n) dinv1[i] = rsqrtf((float)(outdeg[i] + 1));
}

__global__ void wn1_flat(const int* __restrict__ csr_src, const int* __restrict__ csr_dst,
                         const float* __restrict__ dinv1, float* __restrict__ wn, int e) {
  int i = blockIdx.x * blockDim.x + threadIdx.x;
  if (i < e) wn[i] = dinv1[csr_src[i]] * dinv1[csr_dst[i]];
}

// ===================== BN stats (vectorized, LDS-reduced) =====================

#define CS_BLOCKS 512

__global__ __launch_bounds__(256) void colstats_castx(
    const float* __restrict__ A, unsigned short* __restrict__ Abf, int n,
    float* __restrict__ sum, float* __restrict__ sumsq) {
  __shared__ float redS[8][132], redQ[8][132];
  int tid = threadIdx.x;
  int cg = tid & 31, ro = tid >> 5;
  float s[4] = {0.f, 0.f, 0.f, 0.f}, q[4] = {0.f, 0.f, 0.f, 0.f};
  for (int r = blockIdx.x * 8 + ro; r < n; r += gridDim.x * 8) {
    float4 v = *(const float4*)(A + (size_t)r * HD + cg * 4);
    uint2 pk;
    pk.x = packbf(v.x, v.y);
    pk.y = packbf(v.z, v.w);
    *(uint2*)(Abf + (size_t)r * HD + cg * 4) = pk;
    s[0] += v.x; q[0] += v.x * v.x;
    s[1] += v.y; q[1] += v.y * v.y;
    s[2] += v.z; q[2] += v.z * v.z;
    s[3] += v.w; q[3] += v.w * v.w;
  }
#pragma unroll
  for (int i = 0; i < 4; i++) { redS[ro][cg * 4 + i] = s[i]; redQ[ro][cg * 4 + i] = q[i]; }
  __syncthreads();
  if (tid < 128) {
    float ts = 0.f, tq = 0.f;
#pragma unroll
    for (int k = 0; k < 8; k++) { ts += redS[k][tid]; tq += redQ[k][tid]; }
    atomicAdd(&sum[tid], ts);
    atomicAdd(&sumsq[tid], tq);
  }
}

__global__ __launch_bounds__(256) void colstats_bf(
    const unsigned short* __restrict__ A, int n,
    float* __restrict__ sum, float* __restrict__ sumsq) {
  __shared__ float redS[8][132], redQ[8][132];
  int tid = threadIdx.x;
  int cg = tid & 31, ro = tid >> 5;
  float s[4] = {0.f, 0.f, 0.f, 0.f}, q[4] = {0.f, 0.f, 0.f, 0.f};
  for (int r = blockIdx.x * 8 + ro; r < n; r += gridDim.x * 8) {
    uint2 u = *(const uint2*)(A + (size_t)r * HD + cg * 4);
    float v0 = bflo(u.x), v1 = bfhi(u.x), v2 = bflo(u.y), v3 = bfhi(u.y);
    s[0] += v0; q[0] += v0 * v0;
    s[1] += v1; q[1] += v1 * v1;
    s[2] += v2; q[2] += v2 * v2;
    s[3] += v3; q[3] += v3 * v3;
  }
#pragma unroll
  for (int i = 0; i < 4; i++) { redS[ro][cg * 4 + i] = s[i]; redQ[ro][cg * 4 + i] = q[i]; }
  __syncthreads();
  if (tid < 128) {
    float ts = 0.f, tq = 0.f;
#pragma unroll
    for (int k = 0; k < 8; k++) { ts += redS[k][tid]; tq += redQ[k][tid]; }
    atomicAdd(&sum[tid], ts);
    atomicAdd(&sumsq[tid], tq);
  }
}

__global__ __launch_bounds__(256) void colstats_scaled(
    const unsigned short* __restrict__ A, const float* __restrict__ natt, int n,
    float* __restrict__ o4) {
  __shared__ float rSC[8][132], rQC[8][132], rSO[8][132], rQO[8][132];
  int tid = threadIdx.x;
  int cg = tid & 31, ro = tid >> 5;
  float sc[4] = {0.f, 0.f, 0.f, 0.f}, qc[4] = {0.f, 0.f, 0.f, 0.f};
  float so[4] = {0.f, 0.f, 0.f, 0.f}, qo[4] = {0.f, 0.f, 0.f, 0.f};
  for (int r = blockIdx.x * 8 + ro; r < n; r += gridDim.x * 8) {
    uint2 u = *(const uint2*)(A + (size_t)r * HD + cg * 4);
    float2 at = *(const float2*)(natt + r * 2);
    float v[4] = {bflo(u.x), bfhi(u.x), bflo(u.y), bfhi(u.y)};
#pragma unroll
    for (int i = 0; i < 4; i++) {
      float vc = at.x * v[i], vo = at.y * v[i];
      sc[i] += vc; qc[i] += vc * vc;
      so[i] += vo; qo[i] += vo * vo;
    }
  }
#pragma unroll
  for (int i = 0; i < 4; i++) {
    rSC[ro][cg * 4 + i] = sc[i]; rQC[ro][cg * 4 + i] = qc[i];
    rSO[ro][cg * 4 + i] = so[i]; rQO[ro][cg * 4 + i] = qo[i];
  }
  __syncthreads();
  if (tid < 128) {
    float a = 0.f, b = 0.f, c = 0.f, d = 0.f;
#pragma unroll
    for (int k = 0; k < 8; k++) {
      a += rSC[k][tid]; b += rQC[k][tid]; c += rSO[k][tid]; d += rQO[k][tid];
    }
    atomicAdd(&o4[tid], a);
    atomicAdd(&o4[HD + tid], b);
    atomicAdd(&o4[2 * HD + tid], c);
    atomicAdd(&o4[3 * HD + tid], d);
  }
}

// ===================== MFMA GEMM (bf16 in/out, fp32 acc) with fused BN-fold =====================

__global__ __launch_bounds__(256) void gemm_mfma(
    const unsigned short* __restrict__ A, const float* __restrict__ W,
    const float* __restrict__ g, const float* __restrict__ b,
    const float* __restrict__ ssum, const float* __restrict__ ssq, float invN,
    const float* __restrict__ rowscale, int rsStride,
    unsigned short* __restrict__ out, int n, int relu) {
  __shared__ unsigned short WT[128][136];
  __shared__ float sA[HD], tA[HD], tb[HD];
  int tid = threadIdx.x;
  int r00 = blockIdx.x * 128;

  if (tid < HD) {
    float m = ssum[tid] * invN;
    float v = ssq[tid] * invN - m * m;
    float s = g[tid] * rsqrtf(v + 1e-5f);
    sA[tid] = s;
    tA[tid] = b[tid] - m * s;
  }
  __syncthreads();
  for (int idx = tid; idx < 4096; idx += 256) {
    int k = idx >> 5;
    int j4 = (idx & 31) * 4;
    float4 w = *(const float4*)(W + (size_t)k * 128 + j4);
    float s = sA[k];
    WT[j4 + 0][k] = f2bf(w.x * s);
    WT[j4 + 1][k] = f2bf(w.y * s);
    WT[j4 + 2][k] = f2bf(w.z * s);
    WT[j4 + 3][k] = f2bf(w.w * s);
  }
  if (tid < HD) {
    float acc = 0.f;
#pragma unroll 8
    for (int k = 0; k < HD; k++) acc += tA[k] * W[(size_t)k * 128 + tid];
    tb[tid] = acc;
  }
  __syncthreads();

  int w = tid >> 6;
  int l = tid & 63;
  int colb = l & 15;
  int kcb = l >> 4;

#pragma unroll
  for (int rt = 0; rt < 2; rt++) {
    int r0 = r00 + rt * 64;
    if (r0 >= n) break;
    int arow = r0 + w * 16 + colb;
    bool rowok = arow < n;

    f32x4v acc[8];
#pragma unroll
    for (int jt = 0; jt < 8; jt++) acc[jt] = (f32x4v){0.f, 0.f, 0.f, 0.f};

    const unsigned short* Ap = A + (size_t)(rowok ? arow : 0) * 128 + kcb * 8;
#pragma unroll
    for (int kit = 0; kit < 4; kit++) {
      bf16x8v a;
      if (rowok) a = *(const bf16x8v*)(Ap + kit * 32);
      else a = (bf16x8v){0, 0, 0, 0, 0, 0, 0, 0};
#pragma unroll
      for (int jt = 0; jt < 8; jt++) {
        bf16x8v bb = *(const bf16x8v*)&WT[jt * 16 + colb][kit * 32 + kcb * 8];
        acc[jt] = __builtin_amdgcn_mfma_f32_16x16x32_bf16(a, bb, acc[jt], 0, 0, 0);
      }
    }

    int rbase = r0 + w * 16 + kcb * 4;
    float rs[4];
#pragma unroll
    for (int i = 0; i < 4; i++)
      rs[i] = rowscale ? ((rbase + i < n) ? rowscale[(size_t)(rbase + i) * rsStride] : 0.f) : 1.f;
#pragma unroll
    for (int jt = 0; jt < 8; jt++) {
      int colj = jt * 16 + colb;
      float tbv = tb[colj];
#pragma unroll
      for (int i = 0; i < 4; i++) {
        int r = rbase + i;
        if (r < n) {
          float v = acc[jt][i] * rs[i] + tbv;
          if (relu) v = fmaxf(v, 0.f);
          out[(size_t)r * 128 + colj] = f2bf(v);
        }
      }
    }
  }
}

// ===================== GCN aggregation (wave/node, dword lanes, seq weights) =====================

__global__ __launch_bounds__(256) void prop1(
    const unsigned short* __restrict__ z, const int* __restrict__ ptr,
    const int* __restrict__ src, const float* __restrict__ wn,
    const float* __restrict__ dinv, const float* __restrict__ bias,
    unsigned short* __restrict__ out, int n, int relu) {
  int node = blockIdx.x * 4 + (threadIdx.x >> 6);
  if (node >= n) return;
  int lane = threadIdx.x & 63;
  const unsigned int* zp = (const unsigned int*)z;
  float dn = dinv[node];
  float ws = dn * dn;
  unsigned int us = zp[(size_t)node * 64 + lane];
  float a0 = ws * bflo(us), a1 = ws * bfhi(us);
  int e = ptr[node], e1 = ptr[node + 1];
  for (; e + 7 < e1; e += 8) {
    int s[8]; float w[8]; unsigned int u[8];
#pragma unroll
    for (int k = 0; k < 8; k++) { s[k] = src[e + k]; w[k] = wn[e + k]; }
#pragma unroll
    for (int k = 0; k < 8; k++) u[k] = zp[(size_t)s[k] * 64 + lane];
#pragma unroll
    for (int k = 0; k < 8; k++) { a0 += w[k] * bflo(u[k]); a1 += w[k] * bfhi(u[k]); }
  }
  for (; e + 3 < e1; e += 4) {
    int s[4]; float w[4]; unsigned int u[4];
#pragma unroll
    for (int k = 0; k < 4; k++) { s[k] = src[e + k]; w[k] = wn[e + k]; }
#pragma unroll
    for (int k = 0; k < 4; k++) u[k] = zp[(size_t)s[k] * 64 + lane];
#pragma unroll
    for (int k = 0; k < 4; k++) { a0 += w[k] * bflo(u[k]); a1 += w[k] * bfhi(u[k]); }
  }
  for (; e < e1; e++) {
    unsigned int u = zp[(size_t)src[e] * 64 + lane];
    float we = wn[e];
    a0 += we * bflo(u);
    a1 += we * bfhi(u);
  }
  a0 += bias[lane * 2];
  a1 += bias[lane * 2 + 1];
  if (relu) { a0 = fmaxf(a0, 0.f); a1 = fmaxf(a1, 0.f); }
  ((unsigned int*)out)[(size_t)node * 64 + lane] = packbf(a0, a1);
}

// fused xc/xo aggregation; weights prepacked float2 (wc, wo), sequential reads
__global__ __launch_bounds__(256) void prop2(
    const unsigned short* __restrict__ z1, const unsigned short* __restrict__ z2,
    const int* __restrict__ ptr, const int* __restrict__ src,
    const float2* __restrict__ wpack, const float2* __restrict__ ddeg,
    const float* __restrict__ bc, const float* __restrict__ bo,
    unsigned short* __restrict__ xc, unsigned short* __restrict__ xo, int n) {
  int node = blockIdx.x * 4 + (threadIdx.x >> 6);
  if (node >= n) return;
  int lane = threadIdx.x & 63;
  const unsigned int* z1p = (const unsigned int*)z1;
  const unsigned int* z2p = (const unsigned int*)z2;
  float2 dd = ddeg[node];
  float wsc = dd.x * dd.x, wso = dd.y * dd.y;
  unsigned int uc = z1p[(size_t)node * 64 + lane];
  unsigned int uo = z2p[(size_t)node * 64 + lane];
  float c0 = wsc * bflo(uc), c1 = wsc * bfhi(uc);
  float o0 = wso * bflo(uo), o1 = wso * bfhi(uo);
  int e = ptr[node], e1 = ptr[node + 1];
  for (; e + 3 < e1; e += 4) {
    int s[4]; float2 w[4]; unsigned int a[4], b[4];
#pragma unroll
    for (int k = 0; k < 4; k++) { s[k] = src[e + k]; w[k] = wpack[e + k]; }
#pragma unroll
    for (int k = 0; k < 4; k++) {
      a[k] = z1p[(size_t)s[k] * 64 + lane];
      b[k] = z2p[(size_t)s[k] * 64 + lane];
    }
#pragma unroll
    for (int k = 0; k < 4; k++) {
      c0 += w[k].x * bflo(a[k]); c1 += w[k].x * bfhi(a[k]);
      o0 += w[k].y * bflo(b[k]); o1 += w[k].y * bfhi(b[k]);
    }
  }
  for (; e < e1; e++) {
    int s = src[e];
    float2 w = wpack[e];
    unsigned int a = z1p[(size_t)s * 64 + lane];
    unsigned int b = z2p[(size_t)s * 64 + lane];
    c0 += w.x * bflo(a); c1 += w.x * bfhi(a);
    o0 += w.y * bflo(b); o1 += w.y * bfhi(b);
  }
  c0 = fmaxf(c0 + bc[lane * 2], 0.f);
  c1 = fmaxf(c1 + bc[lane * 2 + 1], 0.f);
  o0 = fmaxf(o0 + bo[lane * 2], 0.f);
  o1 = fmaxf(o1 + bo[lane * 2 + 1], 0.f);
  ((unsigned int*)xc)[(size_t)node * 64 + lane] = packbf(c0, c1);
  ((unsigned int*)xo)[(size_t)node * 64 + lane] = packbf(o0, o1);
}

// ===================== attention =====================

__global__ void proj_kernel(const unsigned short* __restrict__ h, const float* __restrict__ We,
                            const float* __restrict__ Wn, const float* __restrict__ bn,
                            float* __restrict__ natt, float* __restrict__ pe, int n) {
  int gtid = blockIdx.x * blockDim.x + threadIdx.x;
  int wave = gtid >> 6;
  int lane = threadIdx.x & 63;
  int nwaves = (gridDim.x * blockDim.x) >> 6;
  const unsigned int* hp = (const unsigned int*)h;
  float4 we0 = *(const float4*)(We + lane * 4);
  float4 we1 = *(const float4*)(We + 256 + lane * 4);
  float4 wn0 = *(const float4*)(Wn + lane * 4);
  for (int node = wave; node < n; node += nwaves) {
    unsigned int u = hp[(size_t)node * 64 + lane];
    float h0 = bflo(u), h1 = bfhi(u);
    float v[6];
    v[0] = h0 * we0.x + h1 * we0.z;
    v[1] = h0 * we0.y + h1 * we0.w;
    v[2] = h0 * we1.x + h1 * we1.z;
    v[3] = h0 * we1.y + h1 * we1.w;
    v[4] = h0 * wn0.x + h1 * wn0.z;
    v[5] = h0 * wn0.y + h1 * wn0.w;
#pragma unroll
    for (int m = 32; m > 0; m >>= 1) {
#pragma unroll
      for (int q = 0; q < 6; q++) v[q] += __shfl_xor(v[q], m, 64);
    }
    if (lane == 0) {
      float q0 = v[4] + bn[0], q1 = v[5] + bn[1];
      float mx = fmaxf(q0, q1);
      float e0 = expf(q0 - mx), e1 = expf(q1 - mx);
      float inv = 1.f / (e0 + e1);
      natt[node * 2 + 0] = e0 * inv;
      natt[node * 2 + 1] = e1 * inv;
      pe[node * 4 + 0] = v[0];
      pe[node * 4 + 1] = v[1];
      pe[node * 4 + 2] = v[2];
      pe[node * 4 + 3] = v[3];
    }
  }
}

__global__ void eatt_flat(const int* __restrict__ row, const int* __restrict__ col,
                          const float* __restrict__ pe, const float* __restrict__ be,
                          float2* __restrict__ eattO, int e) {
  int i = blockIdx.x * blockDim.x + threadIdx.x;
  if (i >= e) return;
  int r = row[i], c = col[i];
  float l0 = pe[r * 4 + 0] + pe[c * 4 + 2] + be[0];
  float l1 = pe[r * 4 + 1] + pe[c * 4 + 3] + be[1];
  float m = fmaxf(l0, l1);
  float e0 = expf(l0 - m), e1 = expf(l1 - m);
  float inv = 1.f / (e0 + e1);
  eattO[i] = make_float2(e0 * inv, e1 * inv);
}

__global__ void deg_kernel(const int* __restrict__ ptrR, const int* __restrict__ csr2_eid,
                           const float2* __restrict__ eattO, float2* __restrict__ ddeg, int n) {
  int gtid = blockIdx.x * blockDim.x + threadIdx.x;
  int node = gtid >> 6;
  int lane = threadIdx.x & 63;
  if (node >= n) return;
  int e0 = ptrR[node], e1 = ptrR[node + 1];
  float sc = 0.f, so = 0.f;
  for (int e = e0 + lane; e < e1; e += 64) {
    float2 at = eattO[csr2_eid[e]];
    sc += at.x; so += at.y;
  }
#pragma unroll
  for (int m = 32; m > 0; m >>= 1) {
    sc += __shfl_xor(sc, m, 64);
    so += __shfl_xor(so, m, 64);
  }
  if (lane == 0) ddeg[node] = make_float2(rsqrtf(1.f + sc), rsqrtf(1.f + so));
}

// normalized per-edge weights packed (wc, wo) — sequential in dest-CSR order
__global__ void wn_flat(const int* __restrict__ csr_src, const int* __restrict__ csr_dst,
                        const int* __restrict__ csr_eid, const float2* __restrict__ eattO,
                        const float2* __restrict__ ddeg, float2* __restrict__ wpack, int e) {
  int i = blockIdx.x * blockDim.x + threadIdx.x;
  if (i >= e) return;
  int s = csr_src[i], c = csr_dst[i];
  float2 at = eattO[csr_eid[i]];
  float2 ds = ddeg[s], dc = ddeg[c];
  wpack[i] = make_float2(ds.x * at.x * dc.x, ds.y * at.y * dc.y);
}

// ===================== pooling =====================

#define POOL_RPB 32

__global__ void pool_kernel(const unsigned short* __restrict__ xc,
                            const unsigned short* __restrict__ xo,
                            const int* __restrict__ batch, int n,
                            float* __restrict__ pc, float* __restrict__ po) {
  int j = threadIdx.x;  // 128
  int r0 = blockIdx.x * POOL_RPB;
  int r1 = min(n, r0 + POOL_RPB);
  if (r0 >= n) return;
  int g = batch[r0];
  float ac = 0.f, ao = 0.f;
  for (int r = r0; r < r1; r++) {
    int br = batch[r];
    if (br != g) {
      atomicAdd(&pc[g * HD + j], ac);
      atomicAdd(&po[g * HD + j], ao);
      ac = 0.f; ao = 0.f; g = br;
    }
    ac += bf2f(xc[(size_t)r * HD + j]);
    ao += bf2f(xo[(size_t)r * HD + j]);
  }
  atomicAdd(&pc[g * HD + j], ac);
  atomicAdd(&po[g * HD + j], ao);
}

// ===================== readout heads =====================

__global__ __launch_bounds__(256) void head1(
    const float* __restrict__ pc, const float* __restrict__ po,
    const float* __restrict__ bn1g, const float* __restrict__ bn1b,
    const float* __restrict__ W1, const float* __restrict__ b1,
    float* __restrict__ Ybuf) {
  int t = blockIdx.x >> 2;
  int jt = blockIdx.x & 3;
  __shared__ float V[128][132];
  __shared__ float Wt[128][33];
  __shared__ float sA[128], tA[128];
  __shared__ float redS[2][128], redQ[2][128];
  int tid = threadIdx.x;

  for (int idx = tid; idx < 16384; idx += 256) {
    int r = idx >> 7, j = idx & 127;
    float v = (t == 0) ? pc[idx] : (t == 1) ? po[idx] : (pc[idx] + po[idx]);
    V[r][j] = v;
  }
  for (int idx = tid; idx < 4096; idx += 256) {
    int k = idx >> 5, c = idx & 31;
    Wt[k][c] = W1[(size_t)t * 16384 + k * 128 + jt * 32 + c];
  }
  __syncthreads();
  {
    int cj = tid & 127, ch = tid >> 7;
    float s = 0.f, q = 0.f;
    for (int r = ch * 64; r < ch * 64 + 64; r++) { float v = V[r][cj]; s += v; q += v * v; }
    redS[ch][cj] = s; redQ[ch][cj] = q;
  }
  __syncthreads();
  if (tid < 128) {
    float s = redS[0][tid] + redS[1][tid];
    float q = redQ[0][tid] + redQ[1][tid];
    float m = s * (1.f / 128.f), var = q * (1.f / 128.f) - m * m;
    float sc = bn1g[t * 128 + tid] * rsqrtf(var + 1e-5f);
    sA[tid] = sc; tA[tid] = bn1b[t * 128 + tid] - m * sc;
  }
  __syncthreads();
  for (int idx = tid; idx < 16384; idx += 256) {
    int r = idx >> 7, j = idx & 127;
    V[r][j] = V[r][j] * sA[j] + tA[j];
  }
  __syncthreads();
  int tr = tid >> 5, tc = tid & 31;
  float acc[16];
#pragma unroll
  for (int i = 0; i < 16; i++) acc[i] = 0.f;
  for (int k = 0; k < 128; k += 4) {
    float w0 = Wt[k][tc], w1 = Wt[k + 1][tc], w2 = Wt[k + 2][tc], w3 = Wt[k + 3][tc];
#pragma unroll
    for (int i = 0; i < 16; i++) {
      float4 v = *(float4*)&V[tr * 16 + i][k];
      acc[i] += v.x * w0 + v.y * w1 + v.z * w2 + v.w * w3;
    }
  }
  float bj = b1[t * 128 + jt * 32 + tc];
#pragma unroll
  for (int i = 0; i < 16; i++) {
    int r = tr * 16 + i;
    Ybuf[(size_t)t * 16384 + r * 128 + jt * 32 + tc] = fmaxf(acc[i] + bj, 0.f);
  }
}

__global__ __launch_bounds__(256) void head2(
    const float* __restrict__ Ybuf,
    const float* __restrict__ bn2g, const float* __restrict__ bn2b,
    const float* __restrict__ W2, const float* __restrict__ b2,
    float* __restrict__ out) {
  int t = blockIdx.x;
  __shared__ float Y[128][132];
  __shared__ float W2s[128][11];
  __shared__ float Z[128][12];
  __shared__ float sA[128], tA[128];
  __shared__ float redS[2][128], redQ[2][128];
  int tid = threadIdx.x;

  for (int idx = tid; idx < 16384; idx += 256) {
    int r = idx >> 7, j = idx & 127;
    Y[r][j] = Ybuf[(size_t)t * 16384 + idx];
  }
  for (int idx = tid; idx < 1280; idx += 256) {
    int k = idx / 10, c = idx % 10;
    W2s[k][c] = W2[(size_t)t * 1280 + idx];
  }
  __syncthreads();
  {
    int cj = tid & 127, ch = tid >> 7;
    float s = 0.f, q = 0.f;
    for (int r = ch * 64; r < ch * 64 + 64; r++) { float v = Y[r][cj]; s += v; q += v * v; }
    redS[ch][cj] = s; redQ[ch][cj] = q;
  }
  __syncthreads();
  if (tid < 128) {
    float s = redS[0][tid] + redS[1][tid];
    float q = redQ[0][tid] + redQ[1][tid];
    float m = s * (1.f / 128.f), var = q * (1.f / 128.f) - m * m;
    float sc = bn2g[t * 128 + tid] * rsqrtf(var + 1e-5f);
    sA[tid] = sc; tA[tid] = bn2b[t * 128 + tid] - m * sc;
  }
  __syncthreads();
  for (int idx = tid; idx < 16384; idx += 256) {
    int r = idx >> 7, j = idx & 127;
    Y[r][j] = Y[r][j] * sA[j] + tA[j];
  }
  __syncthreads();
  for (int idx = tid; idx < 1280; idx += 256) {
    int r = idx / 10, c = idx % 10;
    float acc = b2[t * 10 + c];
#pragma unroll 8
    for (int k = 0; k < 128; k++) acc += Y[r][k] * W2s[k][c];
    Z[r][c] = acc;
  }
  __syncthreads();
  if (tid < 128) {
    int r = tid;
    float m = -1e30f;
    for (int c = 0; c < 10; c++) m = fmaxf(m, Z[r][c]);
    float se = 0.f;
    for (int c = 0; c < 10; c++) se += expf(Z[r][c] - m);
    float lse = m + logf(se);
    for (int c = 0; c < 10; c++) out[t * 1280 + r * 10 + c] = Z[r][c] - lse;
  }
}

// ===================== launch =====================

extern "C" void kernel_launch(void* const* d_in, const int* in_sizes, int n_in,
                              void* d_out, int out_size, void* d_ws, size_t ws_size,
                              hipStream_t stream) {
  const int N = in_sizes[0] / HD;
  const int E = in_sizes[1] / 2;
  const int G = out_size / 30;

  const float* x      = (const float*)d_in[0];
  const int*   ei     = (const int*)d_in[1];
  const int*   batch  = (const int*)d_in[2];
  const float* bnfg   = (const float*)d_in[3];
  const float* bnfb   = (const float*)d_in[4];
  const float* Wfeat  = (const float*)d_in[5];
  const float* bnsg   = (const float*)d_in[6];
  const float* bnsb   = (const float*)d_in[7];
  const float* convW  = (const float*)d_in[8];
  const float* convb  = (const float*)d_in[9];
  const float* Weatt  = (const float*)d_in[10];
  const float* beatt  = (const float*)d_in[11];
  const float* Wnatt  = (const float*)d_in[12];
  const float* bnatt  = (const float*)d_in[13];
  const float* bncg   = (const float*)d_in[14];
  const float* bncb   = (const float*)d_in[15];
  const float* bnog   = (const float*)d_in[16];
  const float* bnob   = (const float*)d_in[17];
  const float* Wc     = (const float*)d_in[18];
  const float* bc     = (const float*)d_in[19];
  const float* Wo     = (const float*)d_in[20];
  const float* bo     = (const float*)d_in[21];
  const float* robn1g = (const float*)d_in[22];
  const float* robn1b = (const float*)d_in[23];
  const float* roW1   = (const float*)d_in[24];
  const float* rob1   = (const float*)d_in[25];
  const float* robn2g = (const float*)d_in[26];
  const float* robn2b = (const float*)d_in[27];
  const float* roW2   = (const float*)d_in[28];
  const float* rob2   = (const float*)d_in[29];
  float* out = (float*)d_out;

  const int* row = ei;
  const int* col = ei + E;

  char* p = (char*)d_ws;
  auto alloc = [&](size_t bytes) -> void* {
    void* r = (void*)p;
    p += (bytes + 255) & ~(size_t)255;
    return r;
  };
  unsigned short* xbf = (unsigned short*)alloc((size_t)N * HD * 2);
  unsigned short* B0  = (unsigned short*)alloc((size_t)N * HD * 2);
  unsigned short* Xc  = (unsigned short*)alloc((size_t)N * HD * 2);
  unsigned short* Xo  = (unsigned short*)alloc((size_t)N * HD * 2);
  unsigned short* Z1  = (unsigned short*)alloc((size_t)N * HD * 2);
  unsigned short* Z2  = (unsigned short*)alloc((size_t)N * HD * 2);
  float2* eattO  = (float2*)alloc((size_t)E * 8);
  float2* wpack  = (float2*)alloc((size_t)E * 8);
  int*   csr_src = (int*)alloc((size_t)E * 4);
  int*   csr_dst = (int*)alloc((size_t)E * 4);
  int*   csr_eid = (int*)alloc((size_t)E * 4);
  int*   csr2_eid= (int*)alloc((size_t)E * 4);
  float* wn1     = (float*)alloc((size_t)E * 4);
  int*   ptrA    = (int*)alloc((size_t)(N + 1) * 4);
  int*   ptrR    = (int*)alloc((size_t)(N + 1) * 4);
  int*   cursor  = (int*)alloc((size_t)N * 4);
  int*   cursor2 = (int*)alloc((size_t)N * 4);
  int*   cnt_in  = (int*)alloc((size_t)N * 4);
  int*   outdeg  = (int*)alloc((size_t)N * 4);
  float* dinv1   = (float*)alloc((size_t)N * 4);
  float2* ddeg   = (float2*)alloc((size_t)N * 8);
  float* natt    = (float*)alloc((size_t)N * 2 * 4);
  float* pe      = (float*)alloc((size_t)N * 4 * 4);
  float* stats   = (float*)alloc(12 * HD * 4);
  float* pooledc = (float*)alloc((size_t)G * HD * 4);
  float* pooledo = (float*)alloc((size_t)G * HD * 4);
  float* Ybuf    = (float*)alloc((size_t)3 * 128 * 128 * 4);
  int*   csums   = (int*)alloc(64 * 4);
  int*   coffs   = (int*)alloc(64 * 4);
  int*   csums2  = (int*)alloc(64 * 4);
  int*   coffs2  = (int*)alloc(64 * 4);

  const int NCH = (N + 1023) / 1024;

  hipMemsetAsync(stats, 0, 12 * HD * 4, stream);
  hipMemsetAsync(pooledc, 0, (size_t)G * HD * 4, stream);
  hipMemsetAsync(pooledo, 0, (size_t)G * HD * 4, stream);

  // histograms: sliced LDS (dense writes, no atomics) when N fits; else fallback
  if ((N + HSLICE - 1) / HSLICE <= 2560) {
    hist_slice<<<2 * HSLICE, 1024, 0, stream>>>(row, col, cnt_in, outdeg, N, E);
  } else {
    hipMemsetAsync(cnt_in, 0, (size_t)N * 4, stream);
    hipMemsetAsync(outdeg, 0, (size_t)N * 4, stream);
    hist_kernel<<<(E + 255) / 256, 256, 0, stream>>>(row, col, cnt_in, outdeg, E);
  }
  scan1<<<NCH, 256, 0, stream>>>(cnt_in, N, csums);
  scan2<<<1, 64, 0, stream>>>(csums, NCH, coffs);
  scan3<<<NCH, 256, 0, stream>>>(cnt_in, N, coffs, ptrA, cursor);
  scan1<<<NCH, 256, 0, stream>>>(outdeg, N, csums2);
  scan2<<<1, 64, 0, stream>>>(csums2, NCH, coffs2);
  scan3<<<NCH, 256, 0, stream>>>(outdeg, N, coffs2, ptrR, cursor2);
  place_both<<<(E + 255) / 256, 256, 0, stream>>>(row, col, cursor, cursor2,
                                                  csr_src, csr_dst, csr_eid, csr2_eid, E);
  dinv1_kernel<<<(N + 255) / 256, 256, 0, stream>>>(outdeg, dinv1, N);
  wn1_flat<<<(E + 255) / 256, 256, 0, stream>>>(csr_src, csr_dst, dinv1, wn1, E);

  int gblocks = (N + 127) / 128;
  int pblocks = (N + 3) / 4;
  float invN = 1.f / (float)N;

  colstats_castx<<<CS_BLOCKS, 256, 0, stream>>>(x, xbf, N, stats, stats + HD);
  gemm_mfma<<<gblocks, 256, 0, stream>>>(xbf, Wfeat, bnfg, bnfb, stats, stats + HD, invN,
                                         nullptr, 0, B0, N, 1);

  for (int i = 0; i < 3; i++) {
    float* hs = stats + 2 * HD + i * 2 * HD;
    colstats_bf<<<CS_BLOCKS, 256, 0, stream>>>(B0, N, hs, hs + HD);
    gemm_mfma<<<gblocks, 256, 0, stream>>>(B0, convW + (size_t)i * HD * HD,
                                           bnsg + i * HD, bnsb + i * HD, hs, hs + HD, invN,
                                           nullptr, 0, Z1, N, 0);
    prop1<<<pblocks, 256, 0, stream>>>(Z1, ptrA, csr_src, wn1, dinv1, convb + i * HD, B0, N, 1);
  }

  proj_kernel<<<512, 256, 0, stream>>>(B0, Weatt, Wnatt, bnatt, natt, pe, N);
  eatt_flat<<<(E + 255) / 256, 256, 0, stream>>>(row, col, pe, beatt, eattO, E);
  deg_kernel<<<(N * 64 + 255) / 256, 256, 0, stream>>>(ptrR, csr2_eid, eattO, ddeg, N);
  wn_flat<<<(E + 255) / 256, 256, 0, stream>>>(csr_src, csr_dst, csr_eid, eattO, ddeg,
                                               wpack, E);

  float* cs = stats + 8 * HD;
  colstats_scaled<<<CS_BLOCKS, 256, 0, stream>>>(B0, natt, N, cs);
  gemm_mfma<<<gblocks, 256, 0, stream>>>(B0, Wc, bncg, bncb, cs, cs + HD, invN,
                                         natt, 2, Z1, N, 0);
  gemm_mfma<<<gblocks, 256, 0, stream>>>(B0, Wo, bnog, bnob, cs + 2 * HD, cs + 3 * HD, invN,
                                         natt + 1, 2, Z2, N, 0);

  prop2<<<pblocks, 256, 0, stream>>>(Z1, Z2, ptrA, csr_src, wpack, ddeg, bc, bo, Xc, Xo, N);

  pool_kernel<<<(N + POOL_RPB - 1) / POOL_RPB, 128, 0, stream>>>(Xc, Xo, batch, N, pooledc, pooledo);
  head1<<<12, 256, 0, stream>>>(pooledc, pooledo, robn1g, robn1b, roW1, rob1, Ybuf);
  head2<<<3, 256, 0, stream>>>(Ybuf, robn2g, robn2b, roW2, rob2, out);
}

// Round 11
// 687.843 us; speedup vs baseline: 1.1606x; 1.1606x over previous
//
#include <hip/hip_runtime.h>

#define HD 128

typedef __attribute__((ext_vector_type(8))) short bf16x8v;
typedef __attribute__((ext_vector_type(4))) float f32x4v;

__device__ __forceinline__ unsigned short f2bf(float f) {
  unsigned int u = __float_as_uint(f);
  u += 0x7FFFu + ((u >> 16) & 1u);   // RNE
  return (unsigned short)(u >> 16);
}
__device__ __forceinline__ float bf2f(unsigned short h) {
  return __uint_as_float(((unsigned int)h) << 16);
}
__device__ __forceinline__ float bflo(unsigned int u) { return __uint_as_float(u << 16); }
__device__ __forceinline__ float bfhi(unsigned int u) { return __uint_as_float(u & 0xFFFF0000u); }
__device__ __forceinline__ unsigned int packbf(float a, float b) {
  return (unsigned int)f2bf(a) | ((unsigned int)f2bf(b) << 16);
}

// ===================== graph preprocessing =====================

__global__ void hist_kernel(const int* __restrict__ row, const int* __restrict__ col,
                            int* __restrict__ cnt_in, int* __restrict__ outdeg, int e) {
  int i = blockIdx.x * blockDim.x + threadIdx.x;
  if (i < e) { atomicAdd(&cnt_in[col[i]], 1); atomicAdd(&outdeg[row[i]], 1); }
}

__global__ void scan1(const int* __restrict__ cnt, int n, int* __restrict__ sums) {
  __shared__ int lds[256];
  int b = blockIdx.x, t = threadIdx.x;
  int base = b * 1024 + t * 4;
  int s = 0;
#pragma unroll
  for (int m = 0; m < 4; m++) if (base + m < n) s += cnt[base + m];
  lds[t] = s;
  __syncthreads();
  for (int d = 128; d > 0; d >>= 1) {
    if (t < d) lds[t] += lds[t + d];
    __syncthreads();
  }
  if (t == 0) sums[b] = lds[0];
}

__global__ void scan2(const int* __restrict__ sums, int nc, int* __restrict__ off) {
  int l = threadIdx.x;
  int v = (l < nc) ? sums[l] : 0;
  int x = v;
#pragma unroll
  for (int d = 1; d < 64; d <<= 1) {
    int y = __shfl_up(x, d, 64);
    if (l >= d) x += y;
  }
  if (l < nc) off[l] = x - v;  // exclusive
}

__global__ void scan3(const int* __restrict__ cnt, int n, const int* __restrict__ off,
                      int* __restrict__ ptr, int* __restrict__ cursor) {
  __shared__ int lds[256];
  int b = blockIdx.x, t = threadIdx.x;
  int base = b * 1024 + t * 4;
  int v[4], p[4];
#pragma unroll
  for (int m = 0; m < 4; m++) v[m] = (base + m < n) ? cnt[base + m] : 0;
  p[0] = v[0];
#pragma unroll
  for (int m = 1; m < 4; m++) p[m] = p[m - 1] + v[m];
  int tsum = p[3];
  lds[t] = tsum;
  __syncthreads();
  for (int d = 1; d < 256; d <<= 1) {
    int y = 0;
    if (t >= d) y = lds[t - d];
    __syncthreads();
    lds[t] += y;
    __syncthreads();
  }
  int basev = off[b] + lds[t] - tsum;
  if (b == 0 && t == 0) ptr[0] = 0;
#pragma unroll
  for (int m = 0; m < 4; m++) {
    int i = base + m;
    if (i < n) {
      int incl = basev + p[m];
      ptr[i + 1] = incl;
      cursor[i] = incl - v[m];
    }
  }
}

// separate scatter arrays (measured faster than packed int2 in R9)
__global__ void place_both(const int* __restrict__ row, const int* __restrict__ col,
                           int* __restrict__ cursor, int* __restrict__ cursor2,
                           int* __restrict__ csr_src, int* __restrict__ csr_dst,
                           int* __restrict__ csr_eid, int* __restrict__ csr2_eid, int e) {
  int i = blockIdx.x * blockDim.x + threadIdx.x;
  if (i < e) {
    int r = row[i], c = col[i];
    int pos = atomicAdd(&cursor[c], 1);
    csr_src[pos] = r;
    csr_dst[pos] = c;
    csr_eid[pos] = i;
    int pos2 = atomicAdd(&cursor2[r], 1);
    csr2_eid[pos2] = i;
  }
}

__global__ void dinv1_kernel(const int* __restrict__ outdeg, float* __restrict__ dinv1, int n) {
  int i = blockIdx.x * blockDim.x + threadIdx.x;
  if (i < n) dinv1[i] = rsqrtf((float)(outdeg[i] + 1));
}

__global__ void wn1_flat(const int* __restrict__ csr_src, const int* __restrict__ csr_dst,
                         const float* __restrict__ dinv1, float* __restrict__ wn, int e) {
  int i = blockIdx.x * blockDim.x + threadIdx.x;
  if (i < e) wn[i] = dinv1[csr_src[i]] * dinv1[csr_dst[i]];
}

// ===================== BN stats (vectorized, LDS-reduced) =====================

#define CS_BLOCKS 512

__global__ __launch_bounds__(256) void colstats_castx(
    const float* __restrict__ A, unsigned short* __restrict__ Abf, int n,
    float* __restrict__ sum, float* __restrict__ sumsq) {
  __shared__ float redS[8][132], redQ[8][132];
  int tid = threadIdx.x;
  int cg = tid & 31, ro = tid >> 5;
  float s[4] = {0.f, 0.f, 0.f, 0.f}, q[4] = {0.f, 0.f, 0.f, 0.f};
  for (int r = blockIdx.x * 8 + ro; r < n; r += gridDim.x * 8) {
    float4 v = *(const float4*)(A + (size_t)r * HD + cg * 4);
    uint2 pk;
    pk.x = packbf(v.x, v.y);
    pk.y = packbf(v.z, v.w);
    *(uint2*)(Abf + (size_t)r * HD + cg * 4) = pk;
    s[0] += v.x; q[0] += v.x * v.x;
    s[1] += v.y; q[1] += v.y * v.y;
    s[2] += v.z; q[2] += v.z * v.z;
    s[3] += v.w; q[3] += v.w * v.w;
  }
#pragma unroll
  for (int i = 0; i < 4; i++) { redS[ro][cg * 4 + i] = s[i]; redQ[ro][cg * 4 + i] = q[i]; }
  __syncthreads();
  if (tid < 128) {
    float ts = 0.f, tq = 0.f;
#pragma unroll
    for (int k = 0; k < 8; k++) { ts += redS[k][tid]; tq += redQ[k][tid]; }
    atomicAdd(&sum[tid], ts);
    atomicAdd(&sumsq[tid], tq);
  }
}

__global__ __launch_bounds__(256) void colstats_bf(
    const unsigned short* __restrict__ A, int n,
    float* __restrict__ sum, float* __restrict__ sumsq) {
  __shared__ float redS[8][132], redQ[8][132];
  int tid = threadIdx.x;
  int cg = tid & 31, ro = tid >> 5;
  float s[4] = {0.f, 0.f, 0.f, 0.f}, q[4] = {0.f, 0.f, 0.f, 0.f};
  for (int r = blockIdx.x * 8 + ro; r < n; r += gridDim.x * 8) {
    uint2 u = *(const uint2*)(A + (size_t)r * HD + cg * 4);
    float v0 = bflo(u.x), v1 = bfhi(u.x), v2 = bflo(u.y), v3 = bfhi(u.y);
    s[0] += v0; q[0] += v0 * v0;
    s[1] += v1; q[1] += v1 * v1;
    s[2] += v2; q[2] += v2 * v2;
    s[3] += v3; q[3] += v3 * v3;
  }
#pragma unroll
  for (int i = 0; i < 4; i++) { redS[ro][cg * 4 + i] = s[i]; redQ[ro][cg * 4 + i] = q[i]; }
  __syncthreads();
  if (tid < 128) {
    float ts = 0.f, tq = 0.f;
#pragma unroll
    for (int k = 0; k < 8; k++) { ts += redS[k][tid]; tq += redQ[k][tid]; }
    atomicAdd(&sum[tid], ts);
    atomicAdd(&sumsq[tid], tq);
  }
}

__global__ __launch_bounds__(256) void colstats_scaled(
    const unsigned short* __restrict__ A, const float* __restrict__ natt, int n,
    float* __restrict__ o4) {
  __shared__ float rSC[8][132], rQC[8][132], rSO[8][132], rQO[8][132];
  int tid = threadIdx.x;
  int cg = tid & 31, ro = tid >> 5;
  float sc[4] = {0.f, 0.f, 0.f, 0.f}, qc[4] = {0.f, 0.f, 0.f, 0.f};
  float so[4] = {0.f, 0.f, 0.f, 0.f}, qo[4] = {0.f, 0.f, 0.f, 0.f};
  for (int r = blockIdx.x * 8 + ro; r < n; r += gridDim.x * 8) {
    uint2 u = *(const uint2*)(A + (size_t)r * HD + cg * 4);
    float2 at = *(const float2*)(natt + r * 2);
    float v[4] = {bflo(u.x), bfhi(u.x), bflo(u.y), bfhi(u.y)};
#pragma unroll
    for (int i = 0; i < 4; i++) {
      float vc = at.x * v[i], vo = at.y * v[i];
      sc[i] += vc; qc[i] += vc * vc;
      so[i] += vo; qo[i] += vo * vo;
    }
  }
#pragma unroll
  for (int i = 0; i < 4; i++) {
    rSC[ro][cg * 4 + i] = sc[i]; rQC[ro][cg * 4 + i] = qc[i];
    rSO[ro][cg * 4 + i] = so[i]; rQO[ro][cg * 4 + i] = qo[i];
  }
  __syncthreads();
  if (tid < 128) {
    float a = 0.f, b = 0.f, c = 0.f, d = 0.f;
#pragma unroll
    for (int k = 0; k < 8; k++) {
      a += rSC[k][tid]; b += rQC[k][tid]; c += rSO[k][tid]; d += rQO[k][tid];
    }
    atomicAdd(&o4[tid], a);
    atomicAdd(&o4[HD + tid], b);
    atomicAdd(&o4[2 * HD + tid], c);
    atomicAdd(&o4[3 * HD + tid], d);
  }
}

// ===================== MFMA GEMM (bf16 in/out, fp32 acc) with fused BN-fold =====================

__global__ __launch_bounds__(256) void gemm_mfma(
    const unsigned short* __restrict__ A, const float* __restrict__ W,
    const float* __restrict__ g, const float* __restrict__ b,
    const float* __restrict__ ssum, const float* __restrict__ ssq, float invN,
    const float* __restrict__ rowscale, int rsStride,
    unsigned short* __restrict__ out, int n, int relu) {
  __shared__ unsigned short WT[128][136];
  __shared__ float sA[HD], tA[HD], tb[HD];
  int tid = threadIdx.x;
  int r00 = blockIdx.x * 128;

  if (tid < HD) {
    float m = ssum[tid] * invN;
    float v = ssq[tid] * invN - m * m;
    float s = g[tid] * rsqrtf(v + 1e-5f);
    sA[tid] = s;
    tA[tid] = b[tid] - m * s;
  }
  __syncthreads();
  for (int idx = tid; idx < 4096; idx += 256) {
    int k = idx >> 5;
    int j4 = (idx & 31) * 4;
    float4 w = *(const float4*)(W + (size_t)k * 128 + j4);
    float s = sA[k];
    WT[j4 + 0][k] = f2bf(w.x * s);
    WT[j4 + 1][k] = f2bf(w.y * s);
    WT[j4 + 2][k] = f2bf(w.z * s);
    WT[j4 + 3][k] = f2bf(w.w * s);
  }
  if (tid < HD) {
    float acc = 0.f;
#pragma unroll 8
    for (int k = 0; k < HD; k++) acc += tA[k] * W[(size_t)k * 128 + tid];
    tb[tid] = acc;
  }
  __syncthreads();

  int w = tid >> 6;
  int l = tid & 63;
  int colb = l & 15;
  int kcb = l >> 4;

#pragma unroll
  for (int rt = 0; rt < 2; rt++) {
    int r0 = r00 + rt * 64;
    if (r0 >= n) break;
    int arow = r0 + w * 16 + colb;
    bool rowok = arow < n;

    f32x4v acc[8];
#pragma unroll
    for (int jt = 0; jt < 8; jt++) acc[jt] = (f32x4v){0.f, 0.f, 0.f, 0.f};

    const unsigned short* Ap = A + (size_t)(rowok ? arow : 0) * 128 + kcb * 8;
#pragma unroll
    for (int kit = 0; kit < 4; kit++) {
      bf16x8v a;
      if (rowok) a = *(const bf16x8v*)(Ap + kit * 32);
      else a = (bf16x8v){0, 0, 0, 0, 0, 0, 0, 0};
#pragma unroll
      for (int jt = 0; jt < 8; jt++) {
        bf16x8v bb = *(const bf16x8v*)&WT[jt * 16 + colb][kit * 32 + kcb * 8];
        acc[jt] = __builtin_amdgcn_mfma_f32_16x16x32_bf16(a, bb, acc[jt], 0, 0, 0);
      }
    }

    int rbase = r0 + w * 16 + kcb * 4;
    float rs[4];
#pragma unroll
    for (int i = 0; i < 4; i++)
      rs[i] = rowscale ? ((rbase + i < n) ? rowscale[(size_t)(rbase + i) * rsStride] : 0.f) : 1.f;
#pragma unroll
    for (int jt = 0; jt < 8; jt++) {
      int colj = jt * 16 + colb;
      float tbv = tb[colj];
#pragma unroll
      for (int i = 0; i < 4; i++) {
        int r = rbase + i;
        if (r < n) {
          float v = acc[jt][i] * rs[i] + tbv;
          if (relu) v = fmaxf(v, 0.f);
          out[(size_t)r * 128 + colj] = f2bf(v);
        }
      }
    }
  }
}

// ===================== GCN aggregation (wave/node, dword lanes, seq weights) =====================

__global__ __launch_bounds__(256) void prop1(
    const unsigned short* __restrict__ z, const int* __restrict__ ptr,
    const int* __restrict__ src, const float* __restrict__ wn,
    const float* __restrict__ dinv, const float* __restrict__ bias,
    unsigned short* __restrict__ out, int n, int relu) {
  int node = blockIdx.x * 4 + (threadIdx.x >> 6);
  if (node >= n) return;
  int lane = threadIdx.x & 63;
  const unsigned int* zp = (const unsigned int*)z;
  float dn = dinv[node];
  float ws = dn * dn;
  unsigned int us = zp[(size_t)node * 64 + lane];
  float a0 = ws * bflo(us), a1 = ws * bfhi(us);
  int e = ptr[node], e1 = ptr[node + 1];
  for (; e + 7 < e1; e += 8) {
    int s[8]; float w[8]; unsigned int u[8];
#pragma unroll
    for (int k = 0; k < 8; k++) { s[k] = src[e + k]; w[k] = wn[e + k]; }
#pragma unroll
    for (int k = 0; k < 8; k++) u[k] = zp[(size_t)s[k] * 64 + lane];
#pragma unroll
    for (int k = 0; k < 8; k++) { a0 += w[k] * bflo(u[k]); a1 += w[k] * bfhi(u[k]); }
  }
  for (; e + 3 < e1; e += 4) {
    int s[4]; float w[4]; unsigned int u[4];
#pragma unroll
    for (int k = 0; k < 4; k++) { s[k] = src[e + k]; w[k] = wn[e + k]; }
#pragma unroll
    for (int k = 0; k < 4; k++) u[k] = zp[(size_t)s[k] * 64 + lane];
#pragma unroll
    for (int k = 0; k < 4; k++) { a0 += w[k] * bflo(u[k]); a1 += w[k] * bfhi(u[k]); }
  }
  for (; e < e1; e++) {
    unsigned int u = zp[(size_t)src[e] * 64 + lane];
    float we = wn[e];
    a0 += we * bflo(u);
    a1 += we * bfhi(u);
  }
  a0 += bias[lane * 2];
  a1 += bias[lane * 2 + 1];
  if (relu) { a0 = fmaxf(a0, 0.f); a1 = fmaxf(a1, 0.f); }
  ((unsigned int*)out)[(size_t)node * 64 + lane] = packbf(a0, a1);
}

// fused xc/xo aggregation; weights prepacked float2 (wc, wo), sequential reads
__global__ __launch_bounds__(256) void prop2(
    const unsigned short* __restrict__ z1, const unsigned short* __restrict__ z2,
    const int* __restrict__ ptr, const int* __restrict__ src,
    const float2* __restrict__ wpack, const float2* __restrict__ ddeg,
    const float* __restrict__ bc, const float* __restrict__ bo,
    unsigned short* __restrict__ xc, unsigned short* __restrict__ xo, int n) {
  int node = blockIdx.x * 4 + (threadIdx.x >> 6);
  if (node >= n) return;
  int lane = threadIdx.x & 63;
  const unsigned int* z1p = (const unsigned int*)z1;
  const unsigned int* z2p = (const unsigned int*)z2;
  float2 dd = ddeg[node];
  float wsc = dd.x * dd.x, wso = dd.y * dd.y;
  unsigned int uc = z1p[(size_t)node * 64 + lane];
  unsigned int uo = z2p[(size_t)node * 64 + lane];
  float c0 = wsc * bflo(uc), c1 = wsc * bfhi(uc);
  float o0 = wso * bflo(uo), o1 = wso * bfhi(uo);
  int e = ptr[node], e1 = ptr[node + 1];
  for (; e + 3 < e1; e += 4) {
    int s[4]; float2 w[4]; unsigned int a[4], b[4];
#pragma unroll
    for (int k = 0; k < 4; k++) { s[k] = src[e + k]; w[k] = wpack[e + k]; }
#pragma unroll
    for (int k = 0; k < 4; k++) {
      a[k] = z1p[(size_t)s[k] * 64 + lane];
      b[k] = z2p[(size_t)s[k] * 64 + lane];
    }
#pragma unroll
    for (int k = 0; k < 4; k++) {
      c0 += w[k].x * bflo(a[k]); c1 += w[k].x * bfhi(a[k]);
      o0 += w[k].y * bflo(b[k]); o1 += w[k].y * bfhi(b[k]);
    }
  }
  for (; e < e1; e++) {
    int s = src[e];
    float2 w = wpack[e];
    unsigned int a = z1p[(size_t)s * 64 + lane];
    unsigned int b = z2p[(size_t)s * 64 + lane];
    c0 += w.x * bflo(a); c1 += w.x * bfhi(a);
    o0 += w.y * bflo(b); o1 += w.y * bfhi(b);
  }
  c0 = fmaxf(c0 + bc[lane * 2], 0.f);
  c1 = fmaxf(c1 + bc[lane * 2 + 1], 0.f);
  o0 = fmaxf(o0 + bo[lane * 2], 0.f);
  o1 = fmaxf(o1 + bo[lane * 2 + 1], 0.f);
  ((unsigned int*)xc)[(size_t)node * 64 + lane] = packbf(c0, c1);
  ((unsigned int*)xo)[(size_t)node * 64 + lane] = packbf(o0, o1);
}

// ===================== attention =====================

__global__ void proj_kernel(const unsigned short* __restrict__ h, const float* __restrict__ We,
                            const float* __restrict__ Wn, const float* __restrict__ bn,
                            float* __restrict__ natt, float* __restrict__ pe, int n) {
  int gtid = blockIdx.x * blockDim.x + threadIdx.x;
  int wave = gtid >> 6;
  int lane = threadIdx.x & 63;
  int nwaves = (gridDim.x * blockDim.x) >> 6;
  const unsigned int* hp = (const unsigned int*)h;
  float4 we0 = *(const float4*)(We + lane * 4);
  float4 we1 = *(const float4*)(We + 256 + lane * 4);
  float4 wn0 = *(const float4*)(Wn + lane * 4);
  for (int node = wave; node < n; node += nwaves) {
    unsigned int u = hp[(size_t)node * 64 + lane];
    float h0 = bflo(u), h1 = bfhi(u);
    float v[6];
    v[0] = h0 * we0.x + h1 * we0.z;
    v[1] = h0 * we0.y + h1 * we0.w;
    v[2] = h0 * we1.x + h1 * we1.z;
    v[3] = h0 * we1.y + h1 * we1.w;
    v[4] = h0 * wn0.x + h1 * wn0.z;
    v[5] = h0 * wn0.y + h1 * wn0.w;
#pragma unroll
    for (int m = 32; m > 0; m >>= 1) {
#pragma unroll
      for (int q = 0; q < 6; q++) v[q] += __shfl_xor(v[q], m, 64);
    }
    if (lane == 0) {
      float q0 = v[4] + bn[0], q1 = v[5] + bn[1];
      float mx = fmaxf(q0, q1);
      float e0 = expf(q0 - mx), e1 = expf(q1 - mx);
      float inv = 1.f / (e0 + e1);
      natt[node * 2 + 0] = e0 * inv;
      natt[node * 2 + 1] = e1 * inv;
      pe[node * 4 + 0] = v[0];
      pe[node * 4 + 1] = v[1];
      pe[node * 4 + 2] = v[2];
      pe[node * 4 + 3] = v[3];
    }
  }
}

__global__ void eatt_flat(const int* __restrict__ row, const int* __restrict__ col,
                          const float* __restrict__ pe, const float* __restrict__ be,
                          float2* __restrict__ eattO, int e) {
  int i = blockIdx.x * blockDim.x + threadIdx.x;
  if (i >= e) return;
  int r = row[i], c = col[i];
  float l0 = pe[r * 4 + 0] + pe[c * 4 + 2] + be[0];
  float l1 = pe[r * 4 + 1] + pe[c * 4 + 3] + be[1];
  float m = fmaxf(l0, l1);
  float e0 = expf(l0 - m), e1 = expf(l1 - m);
  float inv = 1.f / (e0 + e1);
  eattO[i] = make_float2(e0 * inv, e1 * inv);
}

__global__ void deg_kernel(const int* __restrict__ ptrR, const int* __restrict__ csr2_eid,
                           const float2* __restrict__ eattO, float2* __restrict__ ddeg, int n) {
  int gtid = blockIdx.x * blockDim.x + threadIdx.x;
  int node = gtid >> 6;
  int lane = threadIdx.x & 63;
  if (node >= n) return;
  int e0 = ptrR[node], e1 = ptrR[node + 1];
  float sc = 0.f, so = 0.f;
  for (int e = e0 + lane; e < e1; e += 64) {
    float2 at = eattO[csr2_eid[e]];
    sc += at.x; so += at.y;
  }
#pragma unroll
  for (int m = 32; m > 0; m >>= 1) {
    sc += __shfl_xor(sc, m, 64);
    so += __shfl_xor(so, m, 64);
  }
  if (lane == 0) ddeg[node] = make_float2(rsqrtf(1.f + sc), rsqrtf(1.f + so));
}

// normalized per-edge weights packed (wc, wo) — sequential in dest-CSR order
__global__ void wn_flat(const int* __restrict__ csr_src, const int* __restrict__ csr_dst,
                        const int* __restrict__ csr_eid, const float2* __restrict__ eattO,
                        const float2* __restrict__ ddeg, float2* __restrict__ wpack, int e) {
  int i = blockIdx.x * blockDim.x + threadIdx.x;
  if (i >= e) return;
  int s = csr_src[i], c = csr_dst[i];
  float2 at = eattO[csr_eid[i]];
  float2 ds = ddeg[s], dc = ddeg[c];
  wpack[i] = make_float2(ds.x * at.x * dc.x, ds.y * at.y * dc.y);
}

// ===================== pooling =====================

#define POOL_RPB 32

__global__ void pool_kernel(const unsigned short* __restrict__ xc,
                            const unsigned short* __restrict__ xo,
                            const int* __restrict__ batch, int n,
                            float* __restrict__ pc, float* __restrict__ po) {
  int j = threadIdx.x;  // 128
  int r0 = blockIdx.x * POOL_RPB;
  int r1 = min(n, r0 + POOL_RPB);
  if (r0 >= n) return;
  int g = batch[r0];
  float ac = 0.f, ao = 0.f;
  for (int r = r0; r < r1; r++) {
    int br = batch[r];
    if (br != g) {
      atomicAdd(&pc[g * HD + j], ac);
      atomicAdd(&po[g * HD + j], ao);
      ac = 0.f; ao = 0.f; g = br;
    }
    ac += bf2f(xc[(size_t)r * HD + j]);
    ao += bf2f(xo[(size_t)r * HD + j]);
  }
  atomicAdd(&pc[g * HD + j], ac);
  atomicAdd(&po[g * HD + j], ao);
}

// ===================== readout heads =====================

__global__ __launch_bounds__(256) void head1(
    const float* __restrict__ pc, const float* __restrict__ po,
    const float* __restrict__ bn1g, const float* __restrict__ bn1b,
    const float* __restrict__ W1, const float* __restrict__ b1,
    float* __restrict__ Ybuf) {
  int t = blockIdx.x >> 2;
  int jt = blockIdx.x & 3;
  __shared__ float V[128][132];
  __shared__ float Wt[128][33];
  __shared__ float sA[128], tA[128];
  __shared__ float redS[2][128], redQ[2][128];
  int tid = threadIdx.x;

  for (int idx = tid; idx < 16384; idx += 256) {
    int r = idx >> 7, j = idx & 127;
    float v = (t == 0) ? pc[idx] : (t == 1) ? po[idx] : (pc[idx] + po[idx]);
    V[r][j] = v;
  }
  for (int idx = tid; idx < 4096; idx += 256) {
    int k = idx >> 5, c = idx & 31;
    Wt[k][c] = W1[(size_t)t * 16384 + k * 128 + jt * 32 + c];
  }
  __syncthreads();
  {
    int cj = tid & 127, ch = tid >> 7;
    float s = 0.f, q = 0.f;
    for (int r = ch * 64; r < ch * 64 + 64; r++) { float v = V[r][cj]; s += v; q += v * v; }
    redS[ch][cj] = s; redQ[ch][cj] = q;
  }
  __syncthreads();
  if (tid < 128) {
    float s = redS[0][tid] + redS[1][tid];
    float q = redQ[0][tid] + redQ[1][tid];
    float m = s * (1.f / 128.f), var = q * (1.f / 128.f) - m * m;
    float sc = bn1g[t * 128 + tid] * rsqrtf(var + 1e-5f);
    sA[tid] = sc; tA[tid] = bn1b[t * 128 + tid] - m * sc;
  }
  __syncthreads();
  for (int idx = tid; idx < 16384; idx += 256) {
    int r = idx >> 7, j = idx & 127;
    V[r][j] = V[r][j] * sA[j] + tA[j];
  }
  __syncthreads();
  int tr = tid >> 5, tc = tid & 31;
  float acc[16];
#pragma unroll
  for (int i = 0; i < 16; i++) acc[i] = 0.f;
  for (int k = 0; k < 128; k += 4) {
    float w0 = Wt[k][tc], w1 = Wt[k + 1][tc], w2 = Wt[k + 2][tc], w3 = Wt[k + 3][tc];
#pragma unroll
    for (int i = 0; i < 16; i++) {
      float4 v = *(float4*)&V[tr * 16 + i][k];
      acc[i] += v.x * w0 + v.y * w1 + v.z * w2 + v.w * w3;
    }
  }
  float bj = b1[t * 128 + jt * 32 + tc];
#pragma unroll
  for (int i = 0; i < 16; i++) {
    int r = tr * 16 + i;
    Ybuf[(size_t)t * 16384 + r * 128 + jt * 32 + tc] = fmaxf(acc[i] + bj, 0.f);
  }
}

__global__ __launch_bounds__(256) void head2(
    const float* __restrict__ Ybuf,
    const float* __restrict__ bn2g, const float* __restrict__ bn2b,
    const float* __restrict__ W2, const float* __restrict__ b2,
    float* __restrict__ out) {
  int t = blockIdx.x;
  __shared__ float Y[128][132];
  __shared__ float W2s[128][11];
  __shared__ float Z[128][12];
  __shared__ float sA[128], tA[128];
  __shared__ float redS[2][128], redQ[2][128];
  int tid = threadIdx.x;

  for (int idx = tid; idx < 16384; idx += 256) {
    int r = idx >> 7, j = idx & 127;
    Y[r][j] = Ybuf[(size_t)t * 16384 + idx];
  }
  for (int idx = tid; idx < 1280; idx += 256) {
    int k = idx / 10, c = idx % 10;
    W2s[k][c] = W2[(size_t)t * 1280 + idx];
  }
  __syncthreads();
  {
    int cj = tid & 127, ch = tid >> 7;
    float s = 0.f, q = 0.f;
    for (int r = ch * 64; r < ch * 64 + 64; r++) { float v = Y[r][cj]; s += v; q += v * v; }
    redS[ch][cj] = s; redQ[ch][cj] = q;
  }
  __syncthreads();
  if (tid < 128) {
    float s = redS[0][tid] + redS[1][tid];
    float q = redQ[0][tid] + redQ[1][tid];
    float m = s * (1.f / 128.f), var = q * (1.f / 128.f) - m * m;
    float sc = bn2g[t * 128 + tid] * rsqrtf(var + 1e-5f);
    sA[tid] = sc; tA[tid] = bn2b[t * 128 + tid] - m * sc;
  }
  __syncthreads();
  for (int idx = tid; idx < 16384; idx += 256) {
    int r = idx >> 7, j = idx & 127;
    Y[r][j] = Y[r][j] * sA[j] + tA[j];
  }
  __syncthreads();
  for (int idx = tid; idx < 1280; idx += 256) {
    int r = idx / 10, c = idx % 10;
    float acc = b2[t * 10 + c];
#pragma unroll 8
    for (int k = 0; k < 128; k++) acc += Y[r][k] * W2s[k][c];
    Z[r][c] = acc;
  }
  __syncthreads();
  if (tid < 128) {
    int r = tid;
    float m = -1e30f;
    for (int c = 0; c < 10; c++) m = fmaxf(m, Z[r][c]);
    float se = 0.f;
    for (int c = 0; c < 10; c++) se += expf(Z[r][c] - m);
    float lse = m + logf(se);
    for (int c = 0; c < 10; c++) out[t * 1280 + r * 10 + c] = Z[r][c] - lse;
  }
}

// ===================== launch =====================

extern "C" void kernel_launch(void* const* d_in, const int* in_sizes, int n_in,
                              void* d_out, int out_size, void* d_ws, size_t ws_size,
                              hipStream_t stream) {
  const int N = in_sizes[0] / HD;
  const int E = in_sizes[1] / 2;
  const int G = out_size / 30;

  const float* x      = (const float*)d_in[0];
  const int*   ei     = (const int*)d_in[1];
  const int*   batch  = (const int*)d_in[2];
  const float* bnfg   = (const float*)d_in[3];
  const float* bnfb   = (const float*)d_in[4];
  const float* Wfeat  = (const float*)d_in[5];
  const float* bnsg   = (const float*)d_in[6];
  const float* bnsb   = (const float*)d_in[7];
  const float* convW  = (const float*)d_in[8];
  const float* convb  = (const float*)d_in[9];
  const float* Weatt  = (const float*)d_in[10];
  const float* beatt  = (const float*)d_in[11];
  const float* Wnatt  = (const float*)d_in[12];
  const float* bnatt  = (const float*)d_in[13];
  const float* bncg   = (const float*)d_in[14];
  const float* bncb   = (const float*)d_in[15];
  const float* bnog   = (const float*)d_in[16];
  const float* bnob   = (const float*)d_in[17];
  const float* Wc     = (const float*)d_in[18];
  const float* bc     = (const float*)d_in[19];
  const float* Wo     = (const float*)d_in[20];
  const float* bo     = (const float*)d_in[21];
  const float* robn1g = (const float*)d_in[22];
  const float* robn1b = (const float*)d_in[23];
  const float* roW1   = (const float*)d_in[24];
  const float* rob1   = (const float*)d_in[25];
  const float* robn2g = (const float*)d_in[26];
  const float* robn2b = (const float*)d_in[27];
  const float* roW2   = (const float*)d_in[28];
  const float* rob2   = (const float*)d_in[29];
  float* out = (float*)d_out;

  const int* row = ei;
  const int* col = ei + E;

  char* p = (char*)d_ws;
  auto alloc = [&](size_t bytes) -> void* {
    void* r = (void*)p;
    p += (bytes + 255) & ~(size_t)255;
    return r;
  };
  unsigned short* xbf = (unsigned short*)alloc((size_t)N * HD * 2);
  unsigned short* B0  = (unsigned short*)alloc((size_t)N * HD * 2);
  unsigned short* Xc  = (unsigned short*)alloc((size_t)N * HD * 2);
  unsigned short* Xo  = (unsigned short*)alloc((size_t)N * HD * 2);
  unsigned short* Z1  = (unsigned short*)alloc((size_t)N * HD * 2);
  unsigned short* Z2  = (unsigned short*)alloc((size_t)N * HD * 2);
  float2* eattO  = (float2*)alloc((size_t)E * 8);
  float2* wpack  = (float2*)alloc((size_t)E * 8);
  int*   csr_src = (int*)alloc((size_t)E * 4);
  int*   csr_dst = (int*)alloc((size_t)E * 4);
  int*   csr_eid = (int*)alloc((size_t)E * 4);
  int*   csr2_eid= (int*)alloc((size_t)E * 4);
  float* wn1     = (float*)alloc((size_t)E * 4);
  int*   ptrA    = (int*)alloc((size_t)(N + 1) * 4);
  int*   ptrR    = (int*)alloc((size_t)(N + 1) * 4);
  int*   cursor  = (int*)alloc((size_t)N * 4);
  int*   cursor2 = (int*)alloc((size_t)N * 4);
  int*   cnt_in  = (int*)alloc((size_t)N * 4);
  int*   outdeg  = (int*)alloc((size_t)N * 4);
  float* dinv1   = (float*)alloc((size_t)N * 4);
  float2* ddeg   = (float2*)alloc((size_t)N * 8);
  float* natt    = (float*)alloc((size_t)N * 2 * 4);
  float* pe      = (float*)alloc((size_t)N * 4 * 4);
  float* stats   = (float*)alloc(12 * HD * 4);
  float* pooledc = (float*)alloc((size_t)G * HD * 4);
  float* pooledo = (float*)alloc((size_t)G * HD * 4);
  float* Ybuf    = (float*)alloc((size_t)3 * 128 * 128 * 4);
  int*   csums   = (int*)alloc(64 * 4);
  int*   coffs   = (int*)alloc(64 * 4);
  int*   csums2  = (int*)alloc(64 * 4);
  int*   coffs2  = (int*)alloc(64 * 4);

  const int NCH = (N + 1023) / 1024;

  hipMemsetAsync(cnt_in, 0, (size_t)N * 4, stream);
  hipMemsetAsync(outdeg, 0, (size_t)N * 4, stream);
  hipMemsetAsync(stats, 0, 12 * HD * 4, stream);
  hipMemsetAsync(pooledc, 0, (size_t)G * HD * 4, stream);
  hipMemsetAsync(pooledo, 0, (size_t)G * HD * 4, stream);

  hist_kernel<<<(E + 255) / 256, 256, 0, stream>>>(row, col, cnt_in, outdeg, E);
  scan1<<<NCH, 256, 0, stream>>>(cnt_in, N, csums);
  scan2<<<1, 64, 0, stream>>>(csums, NCH, coffs);
  scan3<<<NCH, 256, 0, stream>>>(cnt_in, N, coffs, ptrA, cursor);
  scan1<<<NCH, 256, 0, stream>>>(outdeg, N, csums2);
  scan2<<<1, 64, 0, stream>>>(csums2, NCH, coffs2);
  scan3<<<NCH, 256, 0, stream>>>(outdeg, N, coffs2, ptrR, cursor2);
  place_both<<<(E + 255) / 256, 256, 0, stream>>>(row, col, cursor, cursor2,
                                                  csr_src, csr_dst, csr_eid, csr2_eid, E);
  dinv1_kernel<<<(N + 255) / 256, 256, 0, stream>>>(outdeg, dinv1, N);
  wn1_flat<<<(E + 255) / 256, 256, 0, stream>>>(csr_src, csr_dst, dinv1, wn1, E);

  int gblocks = (N + 127) / 128;
  int pblocks = (N + 3) / 4;
  float invN = 1.f / (float)N;

  colstats_castx<<<CS_BLOCKS, 256, 0, stream>>>(x, xbf, N, stats, stats + HD);
  gemm_mfma<<<gblocks, 256, 0, stream>>>(xbf, Wfeat, bnfg, bnfb, stats, stats + HD, invN,
                                         nullptr, 0, B0, N, 1);

  for (int i = 0; i < 3; i++) {
    float* hs = stats + 2 * HD + i * 2 * HD;
    colstats_bf<<<CS_BLOCKS, 256, 0, stream>>>(B0, N, hs, hs + HD);
    gemm_mfma<<<gblocks, 256, 0, stream>>>(B0, convW + (size_t)i * HD * HD,
                                           bnsg + i * HD, bnsb + i * HD, hs, hs + HD, invN,
                                           nullptr, 0, Z1, N, 0);
    prop1<<<pblocks, 256, 0, stream>>>(Z1, ptrA, csr_src, wn1, dinv1, convb + i * HD, B0, N, 1);
  }

  proj_kernel<<<512, 256, 0, stream>>>(B0, Weatt, Wnatt, bnatt, natt, pe, N);
  eatt_flat<<<(E + 255) / 256, 256, 0, stream>>>(row, col, pe, beatt, eattO, E);
  deg_kernel<<<(N * 64 + 255) / 256, 256, 0, stream>>>(ptrR, csr2_eid, eattO, ddeg, N);
  wn_flat<<<(E + 255) / 256, 256, 0, stream>>>(csr_src, csr_dst, csr_eid, eattO, ddeg,
                                               wpack, E);

  float* cs = stats + 8 * HD;
  colstats_scaled<<<CS_BLOCKS, 256, 0, stream>>>(B0, natt, N, cs);
  gemm_mfma<<<gblocks, 256, 0, stream>>>(B0, Wc, bncg, bncb, cs, cs + HD, invN,
                                         natt, 2, Z1, N, 0);
  gemm_mfma<<<gblocks, 256, 0, stream>>>(B0, Wo, bnog, bnob, cs + 2 * HD, cs + 3 * HD, invN,
                                         natt + 1, 2, Z2, N, 0);

  prop2<<<pblocks, 256, 0, stream>>>(Z1, Z2, ptrA, csr_src, wpack, ddeg, bc, bo, Xc, Xo, N);

  pool_kernel<<<(N + POOL_RPB - 1) / POOL_RPB, 128, 0, stream>>>(Xc, Xo, batch, N, pooledc, pooledo);
  head1<<<12, 256, 0, stream>>>(pooledc, pooledo, robn1g, robn1b, roW1, rob1, Ybuf);
  head2<<<3, 256, 0, stream>>>(Ybuf, robn2g, robn2b, roW2, rob2, out);
}